// Round 4
// baseline (568.864 us; speedup 1.0000x reference)
//
#include <hip/hip_runtime.h>

#define N_NODES 100000
#define N_EDGES 1600000
#define IN_DIM 64
#define HID_DIM 128
#define EMB_DIM 64

// ---------------- edge dtype handling ----------------
// Reference declares int64 edge_index, but JAX without x64 may give int32.
// Detect on device: little-endian int64 values in [0,1e5) -> every odd dword 0.
__global__ void k_detect_dtype(const unsigned int* __restrict__ ebuf, int* __restrict__ flag) {
    if (blockIdx.x == 0 && threadIdx.x == 0) {
        int is64 = 1;
        for (int i = 0; i < 64; ++i)
            if (ebuf[2 * i + 1] != 0u) { is64 = 0; break; }
        *flag = is64;
    }
}

__device__ __forceinline__ int edge_at(const void* eb, bool is64, long idx) {
    return is64 ? (int)((const long long*)eb)[idx] : ((const int*)eb)[idx];
}

// ---------------- degree count: 4 edges/thread, direct from ebuf -----------
__global__ __launch_bounds__(256) void k_deg(const void* __restrict__ eb,
                                             const int* __restrict__ flag,
                                             int* __restrict__ deg) {
    long e0 = ((long)blockIdx.x * 256 + threadIdx.x) * 4;
    if (e0 >= N_EDGES) return;
    bool is64 = (*flag != 0);
    int c0 = edge_at(eb, is64, N_EDGES + e0 + 0);
    int c1 = edge_at(eb, is64, N_EDGES + e0 + 1);
    int c2 = edge_at(eb, is64, N_EDGES + e0 + 2);
    int c3 = edge_at(eb, is64, N_EDGES + e0 + 3);
    atomicAdd(&deg[c0], 1);
    atomicAdd(&deg[c1], 1);
    atomicAdd(&deg[c2], 1);
    atomicAdd(&deg[c3], 1);
}

__global__ void k_dinv(const int* __restrict__ deg, float* __restrict__ dinv) {
    int i = blockIdx.x * blockDim.x + threadIdx.x;
    if (i < N_NODES) dinv[i] = rsqrtf((float)(deg[i] + 1)); // +1 self loop
}

// ---------------- CSR build: exclusive scan of deg -> off, then fill -------
__global__ __launch_bounds__(1024) void k_scan1(const int* __restrict__ deg,
                                                int* __restrict__ off,
                                                int* __restrict__ bsum) {
    __shared__ int s[1024];
    int i = blockIdx.x * 1024 + threadIdx.x;
    int v = (i < N_NODES) ? deg[i] : 0;
    s[threadIdx.x] = v;
    __syncthreads();
    for (int d = 1; d < 1024; d <<= 1) {           // Hillis-Steele inclusive
        int t = (threadIdx.x >= d) ? s[threadIdx.x - d] : 0;
        __syncthreads();
        s[threadIdx.x] += t;
        __syncthreads();
    }
    if (i < N_NODES) off[i] = s[threadIdx.x] - v;  // exclusive
    if (threadIdx.x == 1023) bsum[blockIdx.x] = s[1023];
}

// exclusive scan of the 98 block sums, parallel (128 threads)
__global__ void k_scan2(int* __restrict__ bsum, int nb) {
    __shared__ int s[128];
    int t = threadIdx.x;
    int v = (t < nb) ? bsum[t] : 0;
    s[t] = v;
    __syncthreads();
    for (int d = 1; d < 128; d <<= 1) {
        int u = (t >= d) ? s[t - d] : 0;
        __syncthreads();
        s[t] += u;
        __syncthreads();
    }
    if (t < nb) bsum[t] = s[t] - v; // exclusive
}

__global__ void k_scan3(int* __restrict__ off, const int* __restrict__ bsum,
                        int* __restrict__ cursor) {
    int i = blockIdx.x * blockDim.x + threadIdx.x;
    if (i < N_NODES) {
        int o = off[i] + bsum[i >> 10];
        off[i] = o;
        cursor[i] = o;
    }
    if (i == 0) off[N_NODES] = N_EDGES;
}

// fill packed CSR entries {src, norm} — one 8B scattered store per edge,
// 4 edges per thread for atomic-latency ILP.
__global__ __launch_bounds__(256) void k_fill(const void* __restrict__ eb,
                                              const int* __restrict__ flag,
                                              const float* __restrict__ dinv,
                                              int* __restrict__ cursor,
                                              int2* __restrict__ csr) {
    long e0 = ((long)blockIdx.x * 256 + threadIdx.x) * 4;
    if (e0 >= N_EDGES) return;
    bool is64 = (*flag != 0);
    int r[4], c[4];
#pragma unroll
    for (int j = 0; j < 4; ++j) {
        r[j] = edge_at(eb, is64, e0 + j);
        c[j] = edge_at(eb, is64, N_EDGES + e0 + j);
    }
    float n[4];
#pragma unroll
    for (int j = 0; j < 4; ++j) n[j] = dinv[r[j]] * dinv[c[j]];
    int p[4];
#pragma unroll
    for (int j = 0; j < 4; ++j) p[j] = atomicAdd(&cursor[c[j]], 1);
#pragma unroll
    for (int j = 0; j < 4; ++j) csr[p[j]] = make_int2(r[j], __float_as_int(n[j]));
}

// ---------------- GEMM1: h1 = x @ W1  (100000x64 @ 64x128) ----------------
__global__ __launch_bounds__(256) void k_gemm1(const float4* __restrict__ x4,
                                               const float4* __restrict__ W14,
                                               float4* __restrict__ h14) {
    __shared__ float sW[IN_DIM * HID_DIM]; // 32 KB
    __shared__ float sX[16 * IN_DIM];      // 4 KB
    float4* sW4 = (float4*)sW;
    float4* sX4 = (float4*)sX;
    int t = threadIdx.x;
    long row0 = (long)blockIdx.x * 16;
    for (int i = t; i < IN_DIM * HID_DIM / 4; i += 256) sW4[i] = W14[i];
    sX4[t] = x4[row0 * (IN_DIM / 4) + t];  // 256 float4 = 16 rows
    __syncthreads();
    int qc = t & 31;        // quad-col: cols [4qc..4qc+3]
    int r  = (t >> 5) * 2;  // rows r, r+1
    float4 a0 = {0,0,0,0}, a1 = {0,0,0,0};
    for (int k = 0; k < IN_DIM; ++k) {
        float4 w = sW4[k * 32 + qc];
        float x0 = sX[r * IN_DIM + k];
        float x1 = sX[(r + 1) * IN_DIM + k];
        a0.x += x0 * w.x; a0.y += x0 * w.y; a0.z += x0 * w.z; a0.w += x0 * w.w;
        a1.x += x1 * w.x; a1.y += x1 * w.y; a1.z += x1 * w.z; a1.w += x1 * w.w;
    }
    h14[(row0 + r) * 32 + qc]     = a0;
    h14[(row0 + r + 1) * 32 + qc] = a1;
}

// ------- agg1: 1 wave/node, lane = channel-pair (float2), x8 unroll --------
__global__ __launch_bounds__(256) void k_agg1(const int* __restrict__ off,
                                              const int2* __restrict__ csr,
                                              const float* __restrict__ dinv,
                                              const float2* __restrict__ h1v,
                                              const float2* __restrict__ b1v,
                                              float2* __restrict__ agg1v) {
    int node = blockIdx.x * 4 + (threadIdx.x >> 6);
    int lane = threadIdx.x & 63;
    if (node >= N_NODES) return;
    float dc = dinv[node];
    float2 b = b1v[lane];
    float2 h = h1v[(long)node * 64 + lane];
    float2 acc;
    acc.x = b.x + dc * dc * h.x;
    acc.y = b.y + dc * dc * h.y;
    int e    = off[node];
    int eend = off[node + 1];
    for (; e + 8 <= eend; e += 8) {
        int2 p0 = csr[e + 0], p1 = csr[e + 1], p2 = csr[e + 2], p3 = csr[e + 3];
        int2 p4 = csr[e + 4], p5 = csr[e + 5], p6 = csr[e + 6], p7 = csr[e + 7];
        float2 v0 = h1v[(long)p0.x * 64 + lane];
        float2 v1 = h1v[(long)p1.x * 64 + lane];
        float2 v2 = h1v[(long)p2.x * 64 + lane];
        float2 v3 = h1v[(long)p3.x * 64 + lane];
        float2 v4 = h1v[(long)p4.x * 64 + lane];
        float2 v5 = h1v[(long)p5.x * 64 + lane];
        float2 v6 = h1v[(long)p6.x * 64 + lane];
        float2 v7 = h1v[(long)p7.x * 64 + lane];
        acc.x += __int_as_float(p0.y) * v0.x; acc.y += __int_as_float(p0.y) * v0.y;
        acc.x += __int_as_float(p1.y) * v1.x; acc.y += __int_as_float(p1.y) * v1.y;
        acc.x += __int_as_float(p2.y) * v2.x; acc.y += __int_as_float(p2.y) * v2.y;
        acc.x += __int_as_float(p3.y) * v3.x; acc.y += __int_as_float(p3.y) * v3.y;
        acc.x += __int_as_float(p4.y) * v4.x; acc.y += __int_as_float(p4.y) * v4.y;
        acc.x += __int_as_float(p5.y) * v5.x; acc.y += __int_as_float(p5.y) * v5.y;
        acc.x += __int_as_float(p6.y) * v6.x; acc.y += __int_as_float(p6.y) * v6.y;
        acc.x += __int_as_float(p7.y) * v7.x; acc.y += __int_as_float(p7.y) * v7.y;
    }
    for (; e < eend; ++e) {
        int2 p = csr[e];
        float n = __int_as_float(p.y);
        float2 v = h1v[(long)p.x * 64 + lane];
        acc.x += n * v.x; acc.y += n * v.y;
    }
    agg1v[(long)node * 64 + lane] = acc;
}

// ---------------- GEMM2: h2 = relu(agg1) @ W2  (100000x128 @ 128x64) ------
__global__ __launch_bounds__(256) void k_gemm2(const float4* __restrict__ agg14,
                                               const float4* __restrict__ W24,
                                               float4* __restrict__ h24) {
    __shared__ float sW[HID_DIM * EMB_DIM]; // 32 KB
    __shared__ float sH[32 * HID_DIM];      // 16 KB
    float4* sW4 = (float4*)sW;
    float4* sH4 = (float4*)sH;
    int t = threadIdx.x;
    long row0 = (long)blockIdx.x * 32;
    for (int i = t; i < HID_DIM * EMB_DIM / 4; i += 256) sW4[i] = W24[i];
    for (int i = t; i < 32 * HID_DIM / 4; i += 256) {
        float4 v = agg14[row0 * (HID_DIM / 4) + i];
        v.x = fmaxf(v.x, 0.f); v.y = fmaxf(v.y, 0.f);
        v.z = fmaxf(v.z, 0.f); v.w = fmaxf(v.w, 0.f);
        sH4[i] = v;
    }
    __syncthreads();
    int qc = t & 15;
    int r  = (t >> 4) * 2;
    float4 a0 = {0,0,0,0}, a1 = {0,0,0,0};
    for (int k = 0; k < HID_DIM; ++k) {
        float4 w = sW4[k * 16 + qc];
        float x0 = sH[r * HID_DIM + k];
        float x1 = sH[(r + 1) * HID_DIM + k];
        a0.x += x0 * w.x; a0.y += x0 * w.y; a0.z += x0 * w.z; a0.w += x0 * w.w;
        a1.x += x1 * w.x; a1.y += x1 * w.y; a1.z += x1 * w.z; a1.w += x1 * w.w;
    }
    h24[(row0 + r) * 16 + qc]     = a0;
    h24[(row0 + r + 1) * 16 + qc] = a1;
}

// ------- agg2: 1 wave/node, lane = channel, x8 unroll ----------------------
__global__ __launch_bounds__(256) void k_agg2(const int* __restrict__ off,
                                              const int2* __restrict__ csr,
                                              const float* __restrict__ dinv,
                                              const float* __restrict__ h2,
                                              const float* __restrict__ b2,
                                              float* __restrict__ out) {
    int node = blockIdx.x * 4 + (threadIdx.x >> 6);
    int c    = threadIdx.x & 63;
    if (node >= N_NODES) return;
    float dc = dinv[node];
    float acc = b2[c] + dc * dc * h2[(long)node * EMB_DIM + c];
    int e    = off[node];
    int eend = off[node + 1];
    for (; e + 8 <= eend; e += 8) {
        int2 p0 = csr[e + 0], p1 = csr[e + 1], p2 = csr[e + 2], p3 = csr[e + 3];
        int2 p4 = csr[e + 4], p5 = csr[e + 5], p6 = csr[e + 6], p7 = csr[e + 7];
        float v0 = h2[(long)p0.x * EMB_DIM + c];
        float v1 = h2[(long)p1.x * EMB_DIM + c];
        float v2 = h2[(long)p2.x * EMB_DIM + c];
        float v3 = h2[(long)p3.x * EMB_DIM + c];
        float v4 = h2[(long)p4.x * EMB_DIM + c];
        float v5 = h2[(long)p5.x * EMB_DIM + c];
        float v6 = h2[(long)p6.x * EMB_DIM + c];
        float v7 = h2[(long)p7.x * EMB_DIM + c];
        acc += __int_as_float(p0.y) * v0 + __int_as_float(p1.y) * v1
             + __int_as_float(p2.y) * v2 + __int_as_float(p3.y) * v3
             + __int_as_float(p4.y) * v4 + __int_as_float(p5.y) * v5
             + __int_as_float(p6.y) * v6 + __int_as_float(p7.y) * v7;
    }
    for (; e < eend; ++e) {
        int2 p = csr[e];
        acc += __int_as_float(p.y) * h2[(long)p.x * EMB_DIM + c];
    }
    out[(long)node * EMB_DIM + c] = acc;
}

extern "C" void kernel_launch(void* const* d_in, const int* in_sizes, int n_in,
                              void* d_out, int out_size, void* d_ws, size_t ws_size,
                              hipStream_t stream) {
    const float* x   = (const float*)d_in[0];
    const void*  eb  = d_in[1];
    const float* W1  = (const float*)d_in[2];
    const float* b1  = (const float*)d_in[3];
    const float* W2  = (const float*)d_in[4];
    const float* b2  = (const float*)d_in[5];
    float* out = (float*)d_out;

    // Workspace layout (bytes):
    char* ws = (char*)d_ws;
    int*   deg    = (int*)  (ws + 0);           //    400,000
    float* dinv   = (float*)(ws + 400000);      //    400,000
    int*   flag   = (int*)  (ws + 800000);      //         16
    int*   bsum   = (int*)  (ws + 800064);      //        512
    int*   off    = (int*)  (ws + 800576);      //    400,004
    int*   cursor = (int*)  (ws + 1200640);     //    400,004 (pad to 1600768)
    int2*  csr    = (int2*) (ws + 1600768);     // 12,800,000
    float* h1     = (float*)(ws + 14400768);    // 51,200,000
    float* agg1   = (float*)(ws + 65600768);    // 51,200,000
    float* h2     = (float*)(ws + 14400768);    // alias h1 (dead after agg1)
    // total: 116,800,768 B

    hipMemsetAsync(deg, 0, N_NODES * sizeof(int), stream);
    k_detect_dtype<<<1, 64, 0, stream>>>((const unsigned int*)eb, flag);
    k_deg<<<(N_EDGES / 4 + 255) / 256, 256, 0, stream>>>(eb, flag, deg);
    k_dinv<<<(N_NODES + 255) / 256, 256, 0, stream>>>(deg, dinv);

    const int nb = (N_NODES + 1023) / 1024; // 98
    k_scan1<<<nb, 1024, 0, stream>>>(deg, off, bsum);
    k_scan2<<<1, 128, 0, stream>>>(bsum, nb);
    k_scan3<<<(N_NODES + 255) / 256, 256, 0, stream>>>(off, bsum, cursor);
    k_fill<<<(N_EDGES / 4 + 255) / 256, 256, 0, stream>>>(eb, flag, dinv, cursor, csr);

    k_gemm1<<<N_NODES / 16, 256, 0, stream>>>((const float4*)x, (const float4*)W1, (float4*)h1);
    k_agg1<<<(N_NODES + 3) / 4, 256, 0, stream>>>(off, csr, dinv,
                                                  (const float2*)h1, (const float2*)b1,
                                                  (float2*)agg1);

    k_gemm2<<<N_NODES / 32, 256, 0, stream>>>((const float4*)agg1, (const float4*)W2, (float4*)h2);
    k_agg2<<<(N_NODES + 3) / 4, 256, 0, stream>>>(off, csr, dinv, h2, b2, out);
}

// Round 5
// 483.230 us; speedup vs baseline: 1.1772x; 1.1772x over previous
//
#include <hip/hip_runtime.h>

#define N_NODES 100000
#define N_EDGES 1600000
#define IN_DIM 64
#define HID_DIM 128
#define EMB_DIM 64

// ---------------- edge dtype handling ----------------
// Reference declares int64 edge_index, but JAX without x64 may give int32.
// Detect on device: little-endian int64 values in [0,1e5) -> every odd dword 0.
__global__ void k_detect_dtype(const unsigned int* __restrict__ ebuf, int* __restrict__ flag) {
    if (blockIdx.x == 0 && threadIdx.x == 0) {
        int is64 = 1;
        for (int i = 0; i < 64; ++i)
            if (ebuf[2 * i + 1] != 0u) { is64 = 0; break; }
        *flag = is64;
    }
}

__device__ __forceinline__ int edge_at(const void* eb, bool is64, long idx) {
    return is64 ? (int)((const long long*)eb)[idx] : ((const int*)eb)[idx];
}

// ---------------- degree count: 1 edge/thread (max wave-level MLP) ---------
__global__ __launch_bounds__(256) void k_deg(const void* __restrict__ eb,
                                             const int* __restrict__ flag,
                                             int* __restrict__ deg) {
    long e = (long)blockIdx.x * 256 + threadIdx.x;
    if (e >= N_EDGES) return;
    bool is64 = (*flag != 0);
    int c = edge_at(eb, is64, N_EDGES + e);
    atomicAdd(&deg[c], 1);
}

__global__ void k_dinv(const int* __restrict__ deg, float* __restrict__ dinv) {
    int i = blockIdx.x * blockDim.x + threadIdx.x;
    if (i < N_NODES) dinv[i] = rsqrtf((float)(deg[i] + 1)); // +1 self loop
}

// ---------------- CSR build: exclusive scan of deg -> off, then fill -------
__global__ __launch_bounds__(1024) void k_scan1(const int* __restrict__ deg,
                                                int* __restrict__ off,
                                                int* __restrict__ bsum) {
    __shared__ int s[1024];
    int i = blockIdx.x * 1024 + threadIdx.x;
    int v = (i < N_NODES) ? deg[i] : 0;
    s[threadIdx.x] = v;
    __syncthreads();
    for (int d = 1; d < 1024; d <<= 1) {           // Hillis-Steele inclusive
        int t = (threadIdx.x >= d) ? s[threadIdx.x - d] : 0;
        __syncthreads();
        s[threadIdx.x] += t;
        __syncthreads();
    }
    if (i < N_NODES) off[i] = s[threadIdx.x] - v;  // exclusive
    if (threadIdx.x == 1023) bsum[blockIdx.x] = s[1023];
}

// exclusive scan of the 98 block sums, parallel (128 threads)
__global__ void k_scan2(int* __restrict__ bsum, int nb) {
    __shared__ int s[128];
    int t = threadIdx.x;
    int v = (t < nb) ? bsum[t] : 0;
    s[t] = v;
    __syncthreads();
    for (int d = 1; d < 128; d <<= 1) {
        int u = (t >= d) ? s[t - d] : 0;
        __syncthreads();
        s[t] += u;
        __syncthreads();
    }
    if (t < nb) bsum[t] = s[t] - v; // exclusive
}

__global__ void k_scan3(int* __restrict__ off, const int* __restrict__ bsum,
                        int* __restrict__ cursor) {
    int i = blockIdx.x * blockDim.x + threadIdx.x;
    if (i < N_NODES) {
        int o = off[i] + bsum[i >> 10];
        off[i] = o;
        cursor[i] = o;
    }
    if (i == 0) off[N_NODES] = N_EDGES;
}

// fill packed CSR entries {src, norm}: 1 edge/thread, one 8B scattered store.
__global__ __launch_bounds__(256) void k_fill(const void* __restrict__ eb,
                                              const int* __restrict__ flag,
                                              const float* __restrict__ dinv,
                                              int* __restrict__ cursor,
                                              int2* __restrict__ csr) {
    long e = (long)blockIdx.x * 256 + threadIdx.x;
    if (e >= N_EDGES) return;
    bool is64 = (*flag != 0);
    int r = edge_at(eb, is64, e);
    int c = edge_at(eb, is64, N_EDGES + e);
    float n = dinv[r] * dinv[c];
    int p = atomicAdd(&cursor[c], 1);
    csr[p] = make_int2(r, __float_as_int(n));
}

// ---------------- GEMM1: h1 = x @ W1  (100000x64 @ 64x128) ----------------
__global__ __launch_bounds__(256) void k_gemm1(const float4* __restrict__ x4,
                                               const float4* __restrict__ W14,
                                               float4* __restrict__ h14) {
    __shared__ float sW[IN_DIM * HID_DIM]; // 32 KB
    __shared__ float sX[16 * IN_DIM];      // 4 KB
    float4* sW4 = (float4*)sW;
    float4* sX4 = (float4*)sX;
    int t = threadIdx.x;
    long row0 = (long)blockIdx.x * 16;
    for (int i = t; i < IN_DIM * HID_DIM / 4; i += 256) sW4[i] = W14[i];
    sX4[t] = x4[row0 * (IN_DIM / 4) + t];  // 256 float4 = 16 rows
    __syncthreads();
    int qc = t & 31;        // quad-col: cols [4qc..4qc+3]
    int r  = (t >> 5) * 2;  // rows r, r+1
    float4 a0 = {0,0,0,0}, a1 = {0,0,0,0};
    for (int k = 0; k < IN_DIM; ++k) {
        float4 w = sW4[k * 32 + qc];
        float x0 = sX[r * IN_DIM + k];
        float x1 = sX[(r + 1) * IN_DIM + k];
        a0.x += x0 * w.x; a0.y += x0 * w.y; a0.z += x0 * w.z; a0.w += x0 * w.w;
        a1.x += x1 * w.x; a1.y += x1 * w.y; a1.z += x1 * w.z; a1.w += x1 * w.w;
    }
    h14[(row0 + r) * 32 + qc]     = a0;
    h14[(row0 + r + 1) * 32 + qc] = a1;
}

// ------- agg1: 1 wave/node; 2 lane-groups x float4; x4 strided unroll ------
// Lanes 0-31 handle even-position edges, lanes 32-63 odd-position edges;
// each lane loads float4 (16B) of the source row. Cross-half shfl reduce.
__global__ __launch_bounds__(256) void k_agg1(const int* __restrict__ off,
                                              const int2* __restrict__ csr,
                                              const float* __restrict__ dinv,
                                              const float4* __restrict__ h1,
                                              const float4* __restrict__ b1,
                                              float4* __restrict__ agg1) {
    int node = blockIdx.x * 4 + (threadIdx.x >> 6);
    if (node >= N_NODES) return;
    int lane = threadIdx.x & 63;
    int grp  = lane >> 5;   // 0..1
    int cpos = lane & 31;   // float4 slot: channels 4*cpos..4*cpos+3
    int ebase = off[node];
    int deg   = off[node + 1] - ebase;
    float4 acc = {0.f, 0.f, 0.f, 0.f};
    int i = grp;
    for (; i + 6 < deg; i += 8) {  // 4 edges per group in flight
        int2 p0 = csr[ebase + i + 0];
        int2 p1 = csr[ebase + i + 2];
        int2 p2 = csr[ebase + i + 4];
        int2 p3 = csr[ebase + i + 6];
        float4 v0 = h1[(long)p0.x * 32 + cpos];
        float4 v1 = h1[(long)p1.x * 32 + cpos];
        float4 v2 = h1[(long)p2.x * 32 + cpos];
        float4 v3 = h1[(long)p3.x * 32 + cpos];
        float n0 = __int_as_float(p0.y), n1 = __int_as_float(p1.y);
        float n2 = __int_as_float(p2.y), n3 = __int_as_float(p3.y);
        acc.x += n0 * v0.x; acc.y += n0 * v0.y; acc.z += n0 * v0.z; acc.w += n0 * v0.w;
        acc.x += n1 * v1.x; acc.y += n1 * v1.y; acc.z += n1 * v1.z; acc.w += n1 * v1.w;
        acc.x += n2 * v2.x; acc.y += n2 * v2.y; acc.z += n2 * v2.z; acc.w += n2 * v2.w;
        acc.x += n3 * v3.x; acc.y += n3 * v3.y; acc.z += n3 * v3.z; acc.w += n3 * v3.w;
    }
    for (; i < deg; i += 2) {
        int2 p = csr[ebase + i];
        float n = __int_as_float(p.y);
        float4 v = h1[(long)p.x * 32 + cpos];
        acc.x += n * v.x; acc.y += n * v.y; acc.z += n * v.z; acc.w += n * v.w;
    }
    // combine the two halves (each holds partial sums for the same channels)
    acc.x += __shfl_xor(acc.x, 32);
    acc.y += __shfl_xor(acc.y, 32);
    acc.z += __shfl_xor(acc.z, 32);
    acc.w += __shfl_xor(acc.w, 32);
    if (grp == 0) {
        float dc = dinv[node];
        float s  = dc * dc;
        float4 h = h1[(long)node * 32 + cpos];
        float4 b = b1[cpos];
        acc.x += b.x + s * h.x; acc.y += b.y + s * h.y;
        acc.z += b.z + s * h.z; acc.w += b.w + s * h.w;
        agg1[(long)node * 32 + cpos] = acc;
    }
}

// ---------------- GEMM2: h2 = relu(agg1) @ W2  (100000x128 @ 128x64) ------
__global__ __launch_bounds__(256) void k_gemm2(const float4* __restrict__ agg14,
                                               const float4* __restrict__ W24,
                                               float4* __restrict__ h24) {
    __shared__ float sW[HID_DIM * EMB_DIM]; // 32 KB
    __shared__ float sH[32 * HID_DIM];      // 16 KB
    float4* sW4 = (float4*)sW;
    float4* sH4 = (float4*)sH;
    int t = threadIdx.x;
    long row0 = (long)blockIdx.x * 32;
    for (int i = t; i < HID_DIM * EMB_DIM / 4; i += 256) sW4[i] = W24[i];
    for (int i = t; i < 32 * HID_DIM / 4; i += 256) {
        float4 v = agg14[row0 * (HID_DIM / 4) + i];
        v.x = fmaxf(v.x, 0.f); v.y = fmaxf(v.y, 0.f);
        v.z = fmaxf(v.z, 0.f); v.w = fmaxf(v.w, 0.f);
        sH4[i] = v;
    }
    __syncthreads();
    int qc = t & 15;
    int r  = (t >> 4) * 2;
    float4 a0 = {0,0,0,0}, a1 = {0,0,0,0};
    for (int k = 0; k < HID_DIM; ++k) {
        float4 w = sW4[k * 16 + qc];
        float x0 = sH[r * HID_DIM + k];
        float x1 = sH[(r + 1) * HID_DIM + k];
        a0.x += x0 * w.x; a0.y += x0 * w.y; a0.z += x0 * w.z; a0.w += x0 * w.w;
        a1.x += x1 * w.x; a1.y += x1 * w.y; a1.z += x1 * w.z; a1.w += x1 * w.w;
    }
    h24[(row0 + r) * 16 + qc]     = a0;
    h24[(row0 + r + 1) * 16 + qc] = a1;
}

// ------- agg2: 1 wave/node; 4 lane-groups x float4; x4 strided unroll ------
__global__ __launch_bounds__(256) void k_agg2(const int* __restrict__ off,
                                              const int2* __restrict__ csr,
                                              const float* __restrict__ dinv,
                                              const float4* __restrict__ h2,
                                              const float4* __restrict__ b2,
                                              float4* __restrict__ out) {
    int node = blockIdx.x * 4 + (threadIdx.x >> 6);
    if (node >= N_NODES) return;
    int lane = threadIdx.x & 63;
    int grp  = lane >> 4;   // 0..3
    int cpos = lane & 15;   // float4 slot: channels 4*cpos..4*cpos+3
    int ebase = off[node];
    int deg   = off[node + 1] - ebase;
    float4 acc = {0.f, 0.f, 0.f, 0.f};
    int i = grp;
    for (; i + 12 < deg; i += 16) {  // 4 edges per group in flight
        int2 p0 = csr[ebase + i + 0];
        int2 p1 = csr[ebase + i + 4];
        int2 p2 = csr[ebase + i + 8];
        int2 p3 = csr[ebase + i + 12];
        float4 v0 = h2[(long)p0.x * 16 + cpos];
        float4 v1 = h2[(long)p1.x * 16 + cpos];
        float4 v2 = h2[(long)p2.x * 16 + cpos];
        float4 v3 = h2[(long)p3.x * 16 + cpos];
        float n0 = __int_as_float(p0.y), n1 = __int_as_float(p1.y);
        float n2 = __int_as_float(p2.y), n3 = __int_as_float(p3.y);
        acc.x += n0 * v0.x; acc.y += n0 * v0.y; acc.z += n0 * v0.z; acc.w += n0 * v0.w;
        acc.x += n1 * v1.x; acc.y += n1 * v1.y; acc.z += n1 * v1.z; acc.w += n1 * v1.w;
        acc.x += n2 * v2.x; acc.y += n2 * v2.y; acc.z += n2 * v2.z; acc.w += n2 * v2.w;
        acc.x += n3 * v3.x; acc.y += n3 * v3.y; acc.z += n3 * v3.z; acc.w += n3 * v3.w;
    }
    for (; i < deg; i += 4) {
        int2 p = csr[ebase + i];
        float n = __int_as_float(p.y);
        float4 v = h2[(long)p.x * 16 + cpos];
        acc.x += n * v.x; acc.y += n * v.y; acc.z += n * v.z; acc.w += n * v.w;
    }
    // combine the four quarter-groups
    acc.x += __shfl_xor(acc.x, 16); acc.y += __shfl_xor(acc.y, 16);
    acc.z += __shfl_xor(acc.z, 16); acc.w += __shfl_xor(acc.w, 16);
    acc.x += __shfl_xor(acc.x, 32); acc.y += __shfl_xor(acc.y, 32);
    acc.z += __shfl_xor(acc.z, 32); acc.w += __shfl_xor(acc.w, 32);
    if (grp == 0) {
        float dc = dinv[node];
        float s  = dc * dc;
        float4 h = h2[(long)node * 16 + cpos];
        float4 b = b2[cpos];
        acc.x += b.x + s * h.x; acc.y += b.y + s * h.y;
        acc.z += b.z + s * h.z; acc.w += b.w + s * h.w;
        out[(long)node * 16 + cpos] = acc;
    }
}

extern "C" void kernel_launch(void* const* d_in, const int* in_sizes, int n_in,
                              void* d_out, int out_size, void* d_ws, size_t ws_size,
                              hipStream_t stream) {
    const float* x   = (const float*)d_in[0];
    const void*  eb  = d_in[1];
    const float* W1  = (const float*)d_in[2];
    const float* b1  = (const float*)d_in[3];
    const float* W2  = (const float*)d_in[4];
    const float* b2  = (const float*)d_in[5];
    float* out = (float*)d_out;

    // Workspace layout (bytes):
    char* ws = (char*)d_ws;
    int*   deg    = (int*)  (ws + 0);           //    400,000
    float* dinv   = (float*)(ws + 400000);      //    400,000
    int*   flag   = (int*)  (ws + 800000);      //         16
    int*   bsum   = (int*)  (ws + 800064);      //        512
    int*   off    = (int*)  (ws + 800576);      //    400,004
    int*   cursor = (int*)  (ws + 1200640);     //    400,004 (pad to 1600768)
    int2*  csr    = (int2*) (ws + 1600768);     // 12,800,000
    float* h1     = (float*)(ws + 14400768);    // 51,200,000
    float* agg1   = (float*)(ws + 65600768);    // 51,200,000
    float* h2     = (float*)(ws + 14400768);    // alias h1 (dead after agg1)
    // total: 116,800,768 B

    hipMemsetAsync(deg, 0, N_NODES * sizeof(int), stream);
    k_detect_dtype<<<1, 64, 0, stream>>>((const unsigned int*)eb, flag);
    k_deg<<<(N_EDGES + 255) / 256, 256, 0, stream>>>(eb, flag, deg);
    k_dinv<<<(N_NODES + 255) / 256, 256, 0, stream>>>(deg, dinv);

    const int nb = (N_NODES + 1023) / 1024; // 98
    k_scan1<<<nb, 1024, 0, stream>>>(deg, off, bsum);
    k_scan2<<<1, 128, 0, stream>>>(bsum, nb);
    k_scan3<<<(N_NODES + 255) / 256, 256, 0, stream>>>(off, bsum, cursor);
    k_fill<<<(N_EDGES + 255) / 256, 256, 0, stream>>>(eb, flag, dinv, cursor, csr);

    k_gemm1<<<N_NODES / 16, 256, 0, stream>>>((const float4*)x, (const float4*)W1, (float4*)h1);
    k_agg1<<<(N_NODES + 3) / 4, 256, 0, stream>>>(off, csr, dinv,
                                                  (const float4*)h1, (const float4*)b1,
                                                  (float4*)agg1);

    k_gemm2<<<N_NODES / 32, 256, 0, stream>>>((const float4*)agg1, (const float4*)W2, (float4*)h2);
    k_agg2<<<(N_NODES + 3) / 4, 256, 0, stream>>>(off, csr, dinv,
                                                  (const float4*)h2, (const float4*)b2,
                                                  (float4*)out);
}

// Round 6
// 479.654 us; speedup vs baseline: 1.1860x; 1.0075x over previous
//
#include <hip/hip_runtime.h>

#define N_NODES 100000
#define N_EDGES 1600000
#define IN_DIM 64
#define HID_DIM 128
#define EMB_DIM 64

typedef unsigned short ushortv8 __attribute__((ext_vector_type(8)));

__device__ __forceinline__ float bf2f(unsigned short u) {
    return __uint_as_float(((unsigned)u) << 16);
}
__device__ __forceinline__ unsigned short f2bf(float f) {
    unsigned u = __float_as_uint(f);
    unsigned r = (u + 0x7FFFu + ((u >> 16) & 1u)) >> 16;  // RNE
    return (unsigned short)r;
}

// ---------------- edge dtype handling ----------------
// Reference declares int64 edge_index, but JAX without x64 may give int32.
// Detect on device: little-endian int64 values in [0,1e5) -> every odd dword 0.
__global__ void k_detect_dtype(const unsigned int* __restrict__ ebuf, int* __restrict__ flag) {
    if (blockIdx.x == 0 && threadIdx.x == 0) {
        int is64 = 1;
        for (int i = 0; i < 64; ++i)
            if (ebuf[2 * i + 1] != 0u) { is64 = 0; break; }
        *flag = is64;
    }
}

__device__ __forceinline__ int edge_at(const void* eb, bool is64, long idx) {
    return is64 ? (int)((const long long*)eb)[idx] : ((const int*)eb)[idx];
}

// ---------------- degree count: 1 edge/thread (max wave-level MLP) ---------
__global__ __launch_bounds__(256) void k_deg(const void* __restrict__ eb,
                                             const int* __restrict__ flag,
                                             int* __restrict__ deg) {
    long e = (long)blockIdx.x * 256 + threadIdx.x;
    if (e >= N_EDGES) return;
    bool is64 = (*flag != 0);
    int c = edge_at(eb, is64, N_EDGES + e);
    atomicAdd(&deg[c], 1);
}

__global__ void k_dinv(const int* __restrict__ deg, float* __restrict__ dinv) {
    int i = blockIdx.x * blockDim.x + threadIdx.x;
    if (i < N_NODES) dinv[i] = rsqrtf((float)(deg[i] + 1)); // +1 self loop
}

// ---------------- CSR build: exclusive scan of deg -> off, then fill -------
__global__ __launch_bounds__(1024) void k_scan1(const int* __restrict__ deg,
                                                int* __restrict__ off,
                                                int* __restrict__ bsum) {
    __shared__ int s[1024];
    int i = blockIdx.x * 1024 + threadIdx.x;
    int v = (i < N_NODES) ? deg[i] : 0;
    s[threadIdx.x] = v;
    __syncthreads();
    for (int d = 1; d < 1024; d <<= 1) {           // Hillis-Steele inclusive
        int t = (threadIdx.x >= d) ? s[threadIdx.x - d] : 0;
        __syncthreads();
        s[threadIdx.x] += t;
        __syncthreads();
    }
    if (i < N_NODES) off[i] = s[threadIdx.x] - v;  // exclusive
    if (threadIdx.x == 1023) bsum[blockIdx.x] = s[1023];
}

// exclusive scan of the 98 block sums, parallel (128 threads)
__global__ void k_scan2(int* __restrict__ bsum, int nb) {
    __shared__ int s[128];
    int t = threadIdx.x;
    int v = (t < nb) ? bsum[t] : 0;
    s[t] = v;
    __syncthreads();
    for (int d = 1; d < 128; d <<= 1) {
        int u = (t >= d) ? s[t - d] : 0;
        __syncthreads();
        s[t] += u;
        __syncthreads();
    }
    if (t < nb) bsum[t] = s[t] - v; // exclusive
}

__global__ void k_scan3(int* __restrict__ off, const int* __restrict__ bsum,
                        int* __restrict__ cursor) {
    int i = blockIdx.x * blockDim.x + threadIdx.x;
    if (i < N_NODES) {
        int o = off[i] + bsum[i >> 10];
        off[i] = o;
        cursor[i] = o;
    }
    if (i == 0) off[N_NODES] = N_EDGES;
}

// fill CSR src list: 1 edge/thread, one 4B scattered store per edge.
__global__ __launch_bounds__(256) void k_fill(const void* __restrict__ eb,
                                              const int* __restrict__ flag,
                                              int* __restrict__ cursor,
                                              int* __restrict__ csr) {
    long e = (long)blockIdx.x * 256 + threadIdx.x;
    if (e >= N_EDGES) return;
    bool is64 = (*flag != 0);
    int r = edge_at(eb, is64, e);
    int c = edge_at(eb, is64, N_EDGES + e);
    int p = atomicAdd(&cursor[c], 1);
    csr[p] = r;
}

// ---------------- GEMM1: h1b = bf16(x @ W1)  (100000x64 @ 64x128) ----------
__global__ __launch_bounds__(256) void k_gemm1(const float4* __restrict__ x4,
                                               const float4* __restrict__ W14,
                                               ushort4* __restrict__ h1b4) {
    __shared__ float sW[IN_DIM * HID_DIM]; // 32 KB
    __shared__ float sX[16 * IN_DIM];      // 4 KB
    float4* sW4 = (float4*)sW;
    float4* sX4 = (float4*)sX;
    int t = threadIdx.x;
    long row0 = (long)blockIdx.x * 16;
    for (int i = t; i < IN_DIM * HID_DIM / 4; i += 256) sW4[i] = W14[i];
    sX4[t] = x4[row0 * (IN_DIM / 4) + t];  // 256 float4 = 16 rows
    __syncthreads();
    int qc = t & 31;        // quad-col: cols [4qc..4qc+3]
    int r  = (t >> 5) * 2;  // rows r, r+1
    float4 a0 = {0,0,0,0}, a1 = {0,0,0,0};
    for (int k = 0; k < IN_DIM; ++k) {
        float4 w = sW4[k * 32 + qc];
        float x0 = sX[r * IN_DIM + k];
        float x1 = sX[(r + 1) * IN_DIM + k];
        a0.x += x0 * w.x; a0.y += x0 * w.y; a0.z += x0 * w.z; a0.w += x0 * w.w;
        a1.x += x1 * w.x; a1.y += x1 * w.y; a1.z += x1 * w.z; a1.w += x1 * w.w;
    }
    ushort4 o0, o1;
    o0.x = f2bf(a0.x); o0.y = f2bf(a0.y); o0.z = f2bf(a0.z); o0.w = f2bf(a0.w);
    o1.x = f2bf(a1.x); o1.y = f2bf(a1.y); o1.z = f2bf(a1.z); o1.w = f2bf(a1.w);
    h1b4[(row0 + r) * 32 + qc]     = o0;
    h1b4[(row0 + r + 1) * 32 + qc] = o1;
}

// ------- agg1: 1 wave/node; 4 lane-groups x ushort8 (bf16x8); x4 unroll ----
// 16 lanes/group cover 128 channels at 16B/lane; 16 gathers in flight/wave.
__global__ __launch_bounds__(256) void k_agg1(const int* __restrict__ off,
                                              const int* __restrict__ csr,
                                              const float* __restrict__ dinv,
                                              const ushortv8* __restrict__ h1b,
                                              const float4* __restrict__ b14,
                                              float4* __restrict__ agg1) {
    int node = blockIdx.x * 4 + (threadIdx.x >> 6);
    if (node >= N_NODES) return;
    int lane = threadIdx.x & 63;
    int grp  = lane >> 4;   // 0..3
    int cpos = lane & 15;   // ushort8 slot: channels 8*cpos..8*cpos+7
    int ebase = off[node];
    int deg   = off[node + 1] - ebase;
    float dc  = dinv[node];
    float acc[8] = {0.f, 0.f, 0.f, 0.f, 0.f, 0.f, 0.f, 0.f};
    int i = grp;
    for (; i + 12 < deg; i += 16) {  // 4 edges per group in flight
        int s0 = csr[ebase + i + 0];
        int s1 = csr[ebase + i + 4];
        int s2 = csr[ebase + i + 8];
        int s3 = csr[ebase + i + 12];
        float n0 = dc * dinv[s0], n1 = dc * dinv[s1];
        float n2 = dc * dinv[s2], n3 = dc * dinv[s3];
        ushortv8 v0 = h1b[(long)s0 * 16 + cpos];
        ushortv8 v1 = h1b[(long)s1 * 16 + cpos];
        ushortv8 v2 = h1b[(long)s2 * 16 + cpos];
        ushortv8 v3 = h1b[(long)s3 * 16 + cpos];
#pragma unroll
        for (int j = 0; j < 8; ++j) acc[j] += n0 * bf2f(v0[j]);
#pragma unroll
        for (int j = 0; j < 8; ++j) acc[j] += n1 * bf2f(v1[j]);
#pragma unroll
        for (int j = 0; j < 8; ++j) acc[j] += n2 * bf2f(v2[j]);
#pragma unroll
        for (int j = 0; j < 8; ++j) acc[j] += n3 * bf2f(v3[j]);
    }
    for (; i < deg; i += 4) {
        int s = csr[ebase + i];
        float n = dc * dinv[s];
        ushortv8 v = h1b[(long)s * 16 + cpos];
#pragma unroll
        for (int j = 0; j < 8; ++j) acc[j] += n * bf2f(v[j]);
    }
    // combine the four quarter-groups (partials for same channels)
#pragma unroll
    for (int j = 0; j < 8; ++j) {
        acc[j] += __shfl_xor(acc[j], 16);
        acc[j] += __shfl_xor(acc[j], 32);
    }
    if (grp == 0) {
        float s = dc * dc;
        ushortv8 hs = h1b[(long)node * 16 + cpos];
        float4 b0 = b14[2 * cpos], b1 = b14[2 * cpos + 1];
        float4 o0, o1;
        o0.x = b0.x + s * bf2f(hs[0]) + acc[0];
        o0.y = b0.y + s * bf2f(hs[1]) + acc[1];
        o0.z = b0.z + s * bf2f(hs[2]) + acc[2];
        o0.w = b0.w + s * bf2f(hs[3]) + acc[3];
        o1.x = b1.x + s * bf2f(hs[4]) + acc[4];
        o1.y = b1.y + s * bf2f(hs[5]) + acc[5];
        o1.z = b1.z + s * bf2f(hs[6]) + acc[6];
        o1.w = b1.w + s * bf2f(hs[7]) + acc[7];
        agg1[(long)node * 32 + 2 * cpos]     = o0;
        agg1[(long)node * 32 + 2 * cpos + 1] = o1;
    }
}

// ---------------- GEMM2: h2 = relu(agg1) @ W2  (100000x128 @ 128x64) ------
__global__ __launch_bounds__(256) void k_gemm2(const float4* __restrict__ agg14,
                                               const float4* __restrict__ W24,
                                               float4* __restrict__ h24) {
    __shared__ float sW[HID_DIM * EMB_DIM]; // 32 KB
    __shared__ float sH[32 * HID_DIM];      // 16 KB
    float4* sW4 = (float4*)sW;
    float4* sH4 = (float4*)sH;
    int t = threadIdx.x;
    long row0 = (long)blockIdx.x * 32;
    for (int i = t; i < HID_DIM * EMB_DIM / 4; i += 256) sW4[i] = W24[i];
    for (int i = t; i < 32 * HID_DIM / 4; i += 256) {
        float4 v = agg14[row0 * (HID_DIM / 4) + i];
        v.x = fmaxf(v.x, 0.f); v.y = fmaxf(v.y, 0.f);
        v.z = fmaxf(v.z, 0.f); v.w = fmaxf(v.w, 0.f);
        sH4[i] = v;
    }
    __syncthreads();
    int qc = t & 15;
    int r  = (t >> 4) * 2;
    float4 a0 = {0,0,0,0}, a1 = {0,0,0,0};
    for (int k = 0; k < HID_DIM; ++k) {
        float4 w = sW4[k * 16 + qc];
        float x0 = sH[r * HID_DIM + k];
        float x1 = sH[(r + 1) * HID_DIM + k];
        a0.x += x0 * w.x; a0.y += x0 * w.y; a0.z += x0 * w.z; a0.w += x0 * w.w;
        a1.x += x1 * w.x; a1.y += x1 * w.y; a1.z += x1 * w.z; a1.w += x1 * w.w;
    }
    h24[(row0 + r) * 16 + qc]     = a0;
    h24[(row0 + r + 1) * 16 + qc] = a1;
}

// ------- agg2: 1 wave/node; 4 lane-groups x float4; x4 strided unroll ------
__global__ __launch_bounds__(256) void k_agg2(const int* __restrict__ off,
                                              const int* __restrict__ csr,
                                              const float* __restrict__ dinv,
                                              const float4* __restrict__ h2,
                                              const float4* __restrict__ b2,
                                              float4* __restrict__ out) {
    int node = blockIdx.x * 4 + (threadIdx.x >> 6);
    if (node >= N_NODES) return;
    int lane = threadIdx.x & 63;
    int grp  = lane >> 4;   // 0..3
    int cpos = lane & 15;   // float4 slot: channels 4*cpos..4*cpos+3
    int ebase = off[node];
    int deg   = off[node + 1] - ebase;
    float dc  = dinv[node];
    float4 acc = {0.f, 0.f, 0.f, 0.f};
    int i = grp;
    for (; i + 12 < deg; i += 16) {  // 4 edges per group in flight
        int s0 = csr[ebase + i + 0];
        int s1 = csr[ebase + i + 4];
        int s2 = csr[ebase + i + 8];
        int s3 = csr[ebase + i + 12];
        float n0 = dc * dinv[s0], n1 = dc * dinv[s1];
        float n2 = dc * dinv[s2], n3 = dc * dinv[s3];
        float4 v0 = h2[(long)s0 * 16 + cpos];
        float4 v1 = h2[(long)s1 * 16 + cpos];
        float4 v2 = h2[(long)s2 * 16 + cpos];
        float4 v3 = h2[(long)s3 * 16 + cpos];
        acc.x += n0 * v0.x; acc.y += n0 * v0.y; acc.z += n0 * v0.z; acc.w += n0 * v0.w;
        acc.x += n1 * v1.x; acc.y += n1 * v1.y; acc.z += n1 * v1.z; acc.w += n1 * v1.w;
        acc.x += n2 * v2.x; acc.y += n2 * v2.y; acc.z += n2 * v2.z; acc.w += n2 * v2.w;
        acc.x += n3 * v3.x; acc.y += n3 * v3.y; acc.z += n3 * v3.z; acc.w += n3 * v3.w;
    }
    for (; i < deg; i += 4) {
        int s = csr[ebase + i];
        float n = dc * dinv[s];
        float4 v = h2[(long)s * 16 + cpos];
        acc.x += n * v.x; acc.y += n * v.y; acc.z += n * v.z; acc.w += n * v.w;
    }
    acc.x += __shfl_xor(acc.x, 16); acc.y += __shfl_xor(acc.y, 16);
    acc.z += __shfl_xor(acc.z, 16); acc.w += __shfl_xor(acc.w, 16);
    acc.x += __shfl_xor(acc.x, 32); acc.y += __shfl_xor(acc.y, 32);
    acc.z += __shfl_xor(acc.z, 32); acc.w += __shfl_xor(acc.w, 32);
    if (grp == 0) {
        float s  = dc * dc;
        float4 h = h2[(long)node * 16 + cpos];
        float4 b = b2[cpos];
        acc.x += b.x + s * h.x; acc.y += b.y + s * h.y;
        acc.z += b.z + s * h.z; acc.w += b.w + s * h.w;
        out[(long)node * 16 + cpos] = acc;
    }
}

extern "C" void kernel_launch(void* const* d_in, const int* in_sizes, int n_in,
                              void* d_out, int out_size, void* d_ws, size_t ws_size,
                              hipStream_t stream) {
    const float* x   = (const float*)d_in[0];
    const void*  eb  = d_in[1];
    const float* W1  = (const float*)d_in[2];
    const float* b1  = (const float*)d_in[3];
    const float* W2  = (const float*)d_in[4];
    const float* b2  = (const float*)d_in[5];
    float* out = (float*)d_out;

    // Workspace layout (bytes):
    char* ws = (char*)d_ws;
    int*            deg    = (int*)   (ws + 0);          //    400,000
    float*          dinv   = (float*) (ws + 400000);     //    400,000
    int*            flag   = (int*)   (ws + 800000);     //         16
    int*            bsum   = (int*)   (ws + 800064);     //        512
    int*            off    = (int*)   (ws + 800576);     //    400,004
    int*            cursor = (int*)   (ws + 1200640);    //    400,004 (pad to 1600768)
    int*            csr    = (int*)   (ws + 1600768);    //  6,400,000 -> 8,000,768
    unsigned short* h1b    = (unsigned short*)(ws + 8000768);   // 25,600,000 -> 33,600,768
    float*          agg1   = (float*) (ws + 33600768);   // 51,200,000 -> 84,800,768
    float*          h2     = (float*) (ws + 8000768);    // alias h1b (dead after agg1)
    // total: 84,800,768 B

    hipMemsetAsync(deg, 0, N_NODES * sizeof(int), stream);
    k_detect_dtype<<<1, 64, 0, stream>>>((const unsigned int*)eb, flag);
    k_deg<<<(N_EDGES + 255) / 256, 256, 0, stream>>>(eb, flag, deg);
    k_dinv<<<(N_NODES + 255) / 256, 256, 0, stream>>>(deg, dinv);

    const int nb = (N_NODES + 1023) / 1024; // 98
    k_scan1<<<nb, 1024, 0, stream>>>(deg, off, bsum);
    k_scan2<<<1, 128, 0, stream>>>(bsum, nb);
    k_scan3<<<(N_NODES + 255) / 256, 256, 0, stream>>>(off, bsum, cursor);
    k_fill<<<(N_EDGES + 255) / 256, 256, 0, stream>>>(eb, flag, cursor, csr);

    k_gemm1<<<N_NODES / 16, 256, 0, stream>>>((const float4*)x, (const float4*)W1,
                                              (ushort4*)h1b);
    k_agg1<<<(N_NODES + 3) / 4, 256, 0, stream>>>(off, csr, dinv,
                                                  (const ushortv8*)h1b, (const float4*)b1,
                                                  (float4*)agg1);

    k_gemm2<<<N_NODES / 32, 256, 0, stream>>>((const float4*)agg1, (const float4*)W2,
                                              (float4*)h2);
    k_agg2<<<(N_NODES + 3) / 4, 256, 0, stream>>>(off, csr, dinv,
                                                  (const float4*)h2, (const float4*)b2,
                                                  (float4*)out);
}

// Round 7
// 466.590 us; speedup vs baseline: 1.2192x; 1.0280x over previous
//
#include <hip/hip_runtime.h>

#define N_NODES 100000
#define N_EDGES 1600000
#define IN_DIM 64
#define HID_DIM 128
#define EMB_DIM 64
#define NBUCK 782            // ceil(N_NODES / 128)
#define NSUB  (NBUCK * 8)    // 6256 (bucket x virtual-channel)

typedef unsigned short ushortv8 __attribute__((ext_vector_type(8)));

__device__ __forceinline__ float bf2f(unsigned short u) {
    return __uint_as_float(((unsigned)u) << 16);
}
__device__ __forceinline__ unsigned short f2bf(float f) {
    unsigned u = __float_as_uint(f);
    unsigned r = (u + 0x7FFFu + ((u >> 16) & 1u)) >> 16;  // RNE
    return (unsigned short)r;
}

// ---------------- edge dtype handling ----------------
// Reference declares int64 edge_index, but JAX without x64 may give int32.
// Detect on device: little-endian int64 values in [0,1e5) -> every odd dword 0.
__global__ void k_detect_dtype(const unsigned int* __restrict__ ebuf, int* __restrict__ flag) {
    if (blockIdx.x == 0 && threadIdx.x == 0) {
        int is64 = 1;
        for (int i = 0; i < 64; ++i)
            if (ebuf[2 * i + 1] != 0u) { is64 = 0; break; }
        *flag = is64;
    }
}

__device__ __forceinline__ int edge_at(const void* eb, bool is64, long idx) {
    return is64 ? (int)((const long long*)eb)[idx] : ((const int*)eb)[idx];
}

// ------- pass 1: histogram per (bucket, virtual channel) -------------------
// v = blockIdx.x & 7 is DETERMINISTIC and identical in k_bscatter (same grid,
// same edge->thread map), so sub-range sizing always matches. Locality with
// the physical XCD is a best-effort heuristic (default round-robin dispatch).
__global__ __launch_bounds__(256) void k_bhist(const void* __restrict__ eb,
                                               const int* __restrict__ flag,
                                               int* __restrict__ bcnt) {
    long e = (long)blockIdx.x * 256 + threadIdx.x;
    if (e >= N_EDGES) return;
    bool is64 = (*flag != 0);
    int c = edge_at(eb, is64, N_EDGES + e);
    int v = blockIdx.x & 7;
    atomicAdd(&bcnt[(c >> 7) * 8 + v], 1);
}

// ------- pass 2: exclusive scan of the 6256 sub-range counts ---------------
__global__ __launch_bounds__(1024) void k_bscan(const int* __restrict__ bcnt,
                                                int* __restrict__ base,
                                                int* __restrict__ bcur,
                                                int* __restrict__ off) {
    __shared__ int s[1024];
    int t = threadIdx.x;
    int loc[8];
    int sum = 0;
#pragma unroll
    for (int j = 0; j < 8; ++j) {
        int i = t * 8 + j;
        int v = (i < NSUB) ? bcnt[i] : 0;
        loc[j] = sum;          // exclusive within this thread's chunk
        sum += v;
    }
    s[t] = sum;
    __syncthreads();
    for (int d = 1; d < 1024; d <<= 1) {   // Hillis-Steele inclusive
        int u = (t >= d) ? s[t - d] : 0;
        __syncthreads();
        s[t] += u;
        __syncthreads();
    }
    int bexcl = s[t] - sum;
#pragma unroll
    for (int j = 0; j < 8; ++j) {
        int i = t * 8 + j;
        if (i < NSUB) { int b = bexcl + loc[j]; base[i] = b; bcur[i] = b; }
    }
    if (t == 0) { base[NSUB] = N_EDGES; off[N_NODES] = N_EDGES; }
}

// ------- pass 3: scatter packed {src, dst&127} into bucket staging ---------
// One 4B store per edge at the (bucket,channel) frontier: 16 stores fill a
// 64B line before it evicts -> ~6.4 MB of write traffic instead of ~102 MB.
__global__ __launch_bounds__(256) void k_bscatter(const void* __restrict__ eb,
                                                  const int* __restrict__ flag,
                                                  int* __restrict__ bcur,
                                                  unsigned* __restrict__ stage) {
    long e = (long)blockIdx.x * 256 + threadIdx.x;
    if (e >= N_EDGES) return;
    bool is64 = (*flag != 0);
    int r = edge_at(eb, is64, e);
    int c = edge_at(eb, is64, N_EDGES + e);
    int v = blockIdx.x & 7;
    int p = atomicAdd(&bcur[(c >> 7) * 8 + v], 1);
    stage[p] = (unsigned)r | ((unsigned)(c & 127) << 17);   // src<2^17
}

// ------- pass 4: per-bucket finalize: off[], dinv[], csr[] -----------------
__global__ __launch_bounds__(256) void k_bfinal(const unsigned* __restrict__ stage,
                                                const int* __restrict__ base,
                                                int* __restrict__ off,
                                                float* __restrict__ dinv,
                                                int* __restrict__ csr) {
    __shared__ int h[128];
    __shared__ int lcur[128];
    int b = blockIdx.x;
    int t = threadIdx.x;
    int ebase = base[b * 8];
    int eend  = base[(b + 1) * 8];
    if (t < 128) h[t] = 0;
    __syncthreads();
    for (int i = ebase + t; i < eend; i += 256)
        atomicAdd(&h[stage[i] >> 17], 1);
    __syncthreads();
    int cnt = (t < 128) ? h[t] : 0;
    for (int d = 1; d < 128; d <<= 1) {    // inclusive scan (all threads barrier)
        int u = (t < 128 && t >= d) ? h[t - d] : 0;
        __syncthreads();
        if (t < 128) h[t] += u;
        __syncthreads();
    }
    if (t < 128) {
        int node = b * 128 + t;
        int excl = h[t] - cnt;
        lcur[t] = ebase + excl;
        if (node < N_NODES) {
            off[node]  = ebase + excl;
            dinv[node] = rsqrtf((float)(cnt + 1));  // +1 self loop
        }
    }
    __syncthreads();
    for (int i = ebase + t; i < eend; i += 256) {
        unsigned u = stage[i];
        int p = atomicAdd(&lcur[u >> 17], 1);
        csr[p] = (int)(u & 0x1FFFFu);
    }
}

// ---------------- GEMM1: h1b = bf16(x @ W1)  (100000x64 @ 64x128) ----------
__global__ __launch_bounds__(256) void k_gemm1(const float4* __restrict__ x4,
                                               const float4* __restrict__ W14,
                                               ushort4* __restrict__ h1b4) {
    __shared__ float sW[IN_DIM * HID_DIM]; // 32 KB
    __shared__ float sX[16 * IN_DIM];      // 4 KB
    float4* sW4 = (float4*)sW;
    float4* sX4 = (float4*)sX;
    int t = threadIdx.x;
    long row0 = (long)blockIdx.x * 16;
    for (int i = t; i < IN_DIM * HID_DIM / 4; i += 256) sW4[i] = W14[i];
    sX4[t] = x4[row0 * (IN_DIM / 4) + t];  // 256 float4 = 16 rows
    __syncthreads();
    int qc = t & 31;
    int r  = (t >> 5) * 2;
    float4 a0 = {0,0,0,0}, a1 = {0,0,0,0};
    for (int k = 0; k < IN_DIM; ++k) {
        float4 w = sW4[k * 32 + qc];
        float x0 = sX[r * IN_DIM + k];
        float x1 = sX[(r + 1) * IN_DIM + k];
        a0.x += x0 * w.x; a0.y += x0 * w.y; a0.z += x0 * w.z; a0.w += x0 * w.w;
        a1.x += x1 * w.x; a1.y += x1 * w.y; a1.z += x1 * w.z; a1.w += x1 * w.w;
    }
    ushort4 o0, o1;
    o0.x = f2bf(a0.x); o0.y = f2bf(a0.y); o0.z = f2bf(a0.z); o0.w = f2bf(a0.w);
    o1.x = f2bf(a1.x); o1.y = f2bf(a1.y); o1.z = f2bf(a1.z); o1.w = f2bf(a1.w);
    h1b4[(row0 + r) * 32 + qc]     = o0;
    h1b4[(row0 + r + 1) * 32 + qc] = o1;
}

// ------- agg1: 1 wave/node; 4 lane-groups x ushort8 (bf16x8); x4 unroll ----
__global__ __launch_bounds__(256) void k_agg1(const int* __restrict__ off,
                                              const int* __restrict__ csr,
                                              const float* __restrict__ dinv,
                                              const ushortv8* __restrict__ h1b,
                                              const float4* __restrict__ b14,
                                              float4* __restrict__ agg1) {
    int node = blockIdx.x * 4 + (threadIdx.x >> 6);
    if (node >= N_NODES) return;
    int lane = threadIdx.x & 63;
    int grp  = lane >> 4;
    int cpos = lane & 15;
    int ebase = off[node];
    int deg   = off[node + 1] - ebase;
    float dc  = dinv[node];
    float acc[8] = {0.f, 0.f, 0.f, 0.f, 0.f, 0.f, 0.f, 0.f};
    int i = grp;
    for (; i + 12 < deg; i += 16) {
        int s0 = csr[ebase + i + 0];
        int s1 = csr[ebase + i + 4];
        int s2 = csr[ebase + i + 8];
        int s3 = csr[ebase + i + 12];
        float n0 = dc * dinv[s0], n1 = dc * dinv[s1];
        float n2 = dc * dinv[s2], n3 = dc * dinv[s3];
        ushortv8 v0 = h1b[(long)s0 * 16 + cpos];
        ushortv8 v1 = h1b[(long)s1 * 16 + cpos];
        ushortv8 v2 = h1b[(long)s2 * 16 + cpos];
        ushortv8 v3 = h1b[(long)s3 * 16 + cpos];
#pragma unroll
        for (int j = 0; j < 8; ++j) acc[j] += n0 * bf2f(v0[j]);
#pragma unroll
        for (int j = 0; j < 8; ++j) acc[j] += n1 * bf2f(v1[j]);
#pragma unroll
        for (int j = 0; j < 8; ++j) acc[j] += n2 * bf2f(v2[j]);
#pragma unroll
        for (int j = 0; j < 8; ++j) acc[j] += n3 * bf2f(v3[j]);
    }
    for (; i < deg; i += 4) {
        int s = csr[ebase + i];
        float n = dc * dinv[s];
        ushortv8 v = h1b[(long)s * 16 + cpos];
#pragma unroll
        for (int j = 0; j < 8; ++j) acc[j] += n * bf2f(v[j]);
    }
#pragma unroll
    for (int j = 0; j < 8; ++j) {
        acc[j] += __shfl_xor(acc[j], 16);
        acc[j] += __shfl_xor(acc[j], 32);
    }
    if (grp == 0) {
        float s = dc * dc;
        ushortv8 hs = h1b[(long)node * 16 + cpos];
        float4 b0 = b14[2 * cpos], b1 = b14[2 * cpos + 1];
        float4 o0, o1;
        o0.x = b0.x + s * bf2f(hs[0]) + acc[0];
        o0.y = b0.y + s * bf2f(hs[1]) + acc[1];
        o0.z = b0.z + s * bf2f(hs[2]) + acc[2];
        o0.w = b0.w + s * bf2f(hs[3]) + acc[3];
        o1.x = b1.x + s * bf2f(hs[4]) + acc[4];
        o1.y = b1.y + s * bf2f(hs[5]) + acc[5];
        o1.z = b1.z + s * bf2f(hs[6]) + acc[6];
        o1.w = b1.w + s * bf2f(hs[7]) + acc[7];
        agg1[(long)node * 32 + 2 * cpos]     = o0;
        agg1[(long)node * 32 + 2 * cpos + 1] = o1;
    }
}

// ---------------- GEMM2: h2 = relu(agg1) @ W2  (100000x128 @ 128x64) ------
__global__ __launch_bounds__(256) void k_gemm2(const float4* __restrict__ agg14,
                                               const float4* __restrict__ W24,
                                               float4* __restrict__ h24) {
    __shared__ float sW[HID_DIM * EMB_DIM]; // 32 KB
    __shared__ float sH[32 * HID_DIM];      // 16 KB
    float4* sW4 = (float4*)sW;
    float4* sH4 = (float4*)sH;
    int t = threadIdx.x;
    long row0 = (long)blockIdx.x * 32;
    for (int i = t; i < HID_DIM * EMB_DIM / 4; i += 256) sW4[i] = W24[i];
    for (int i = t; i < 32 * HID_DIM / 4; i += 256) {
        float4 v = agg14[row0 * (HID_DIM / 4) + i];
        v.x = fmaxf(v.x, 0.f); v.y = fmaxf(v.y, 0.f);
        v.z = fmaxf(v.z, 0.f); v.w = fmaxf(v.w, 0.f);
        sH4[i] = v;
    }
    __syncthreads();
    int qc = t & 15;
    int r  = (t >> 4) * 2;
    float4 a0 = {0,0,0,0}, a1 = {0,0,0,0};
    for (int k = 0; k < HID_DIM; ++k) {
        float4 w = sW4[k * 16 + qc];
        float x0 = sH[r * HID_DIM + k];
        float x1 = sH[(r + 1) * HID_DIM + k];
        a0.x += x0 * w.x; a0.y += x0 * w.y; a0.z += x0 * w.z; a0.w += x0 * w.w;
        a1.x += x1 * w.x; a1.y += x1 * w.y; a1.z += x1 * w.z; a1.w += x1 * w.w;
    }
    h24[(row0 + r) * 16 + qc]     = a0;
    h24[(row0 + r + 1) * 16 + qc] = a1;
}

// ------- agg2: 1 wave/node; 4 lane-groups x float4; x4 strided unroll ------
__global__ __launch_bounds__(256) void k_agg2(const int* __restrict__ off,
                                              const int* __restrict__ csr,
                                              const float* __restrict__ dinv,
                                              const float4* __restrict__ h2,
                                              const float4* __restrict__ b2,
                                              float4* __restrict__ out) {
    int node = blockIdx.x * 4 + (threadIdx.x >> 6);
    if (node >= N_NODES) return;
    int lane = threadIdx.x & 63;
    int grp  = lane >> 4;
    int cpos = lane & 15;
    int ebase = off[node];
    int deg   = off[node + 1] - ebase;
    float dc  = dinv[node];
    float4 acc = {0.f, 0.f, 0.f, 0.f};
    int i = grp;
    for (; i + 12 < deg; i += 16) {
        int s0 = csr[ebase + i + 0];
        int s1 = csr[ebase + i + 4];
        int s2 = csr[ebase + i + 8];
        int s3 = csr[ebase + i + 12];
        float n0 = dc * dinv[s0], n1 = dc * dinv[s1];
        float n2 = dc * dinv[s2], n3 = dc * dinv[s3];
        float4 v0 = h2[(long)s0 * 16 + cpos];
        float4 v1 = h2[(long)s1 * 16 + cpos];
        float4 v2 = h2[(long)s2 * 16 + cpos];
        float4 v3 = h2[(long)s3 * 16 + cpos];
        acc.x += n0 * v0.x; acc.y += n0 * v0.y; acc.z += n0 * v0.z; acc.w += n0 * v0.w;
        acc.x += n1 * v1.x; acc.y += n1 * v1.y; acc.z += n1 * v1.z; acc.w += n1 * v1.w;
        acc.x += n2 * v2.x; acc.y += n2 * v2.y; acc.z += n2 * v2.z; acc.w += n2 * v2.w;
        acc.x += n3 * v3.x; acc.y += n3 * v3.y; acc.z += n3 * v3.z; acc.w += n3 * v3.w;
    }
    for (; i < deg; i += 4) {
        int s = csr[ebase + i];
        float n = dc * dinv[s];
        float4 v = h2[(long)s * 16 + cpos];
        acc.x += n * v.x; acc.y += n * v.y; acc.z += n * v.z; acc.w += n * v.w;
    }
    acc.x += __shfl_xor(acc.x, 16); acc.y += __shfl_xor(acc.y, 16);
    acc.z += __shfl_xor(acc.z, 16); acc.w += __shfl_xor(acc.w, 16);
    acc.x += __shfl_xor(acc.x, 32); acc.y += __shfl_xor(acc.y, 32);
    acc.z += __shfl_xor(acc.z, 32); acc.w += __shfl_xor(acc.w, 32);
    if (grp == 0) {
        float s  = dc * dc;
        float4 h = h2[(long)node * 16 + cpos];
        float4 b = b2[cpos];
        acc.x += b.x + s * h.x; acc.y += b.y + s * h.y;
        acc.z += b.z + s * h.z; acc.w += b.w + s * h.w;
        out[(long)node * 16 + cpos] = acc;
    }
}

extern "C" void kernel_launch(void* const* d_in, const int* in_sizes, int n_in,
                              void* d_out, int out_size, void* d_ws, size_t ws_size,
                              hipStream_t stream) {
    const float* x   = (const float*)d_in[0];
    const void*  eb  = d_in[1];
    const float* W1  = (const float*)d_in[2];
    const float* b1  = (const float*)d_in[3];
    const float* W2  = (const float*)d_in[4];
    const float* b2  = (const float*)d_in[5];
    float* out = (float*)d_out;

    // Workspace layout (bytes):
    char* ws = (char*)d_ws;
    int*            flag  = (int*)     (ws + 0);
    int*            bcnt  = (int*)     (ws + 1024);      // 25,024
    int*            base  = (int*)     (ws + 32768);     // 25,028 (NSUB+1)
    int*            bcur  = (int*)     (ws + 65536);     // 25,024
    int*            off   = (int*)     (ws + 131072);    // 400,004
    float*          dinv  = (float*)   (ws + 532480);    // 400,000
    unsigned*       stage = (unsigned*)(ws + 1048576);   // 6,400,000
    int*            csr   = (int*)     (ws + 8388608);   // 6,400,000
    unsigned short* h1b   = (unsigned short*)(ws + 16777216); // 25,600,000
    float*          agg1  = (float*)   (ws + 43000000);  // 51,200,000 (end 94.2 MB)
    float*          h2    = (float*)   (ws + 16777216);  // alias h1b (dead after agg1)

    hipMemsetAsync(bcnt, 0, NSUB * sizeof(int), stream);
    k_detect_dtype<<<1, 64, 0, stream>>>((const unsigned int*)eb, flag);
    k_bhist<<<N_EDGES / 256, 256, 0, stream>>>(eb, flag, bcnt);
    k_bscan<<<1, 1024, 0, stream>>>(bcnt, base, bcur, off);
    k_bscatter<<<N_EDGES / 256, 256, 0, stream>>>(eb, flag, bcur, stage);
    k_bfinal<<<NBUCK, 256, 0, stream>>>(stage, base, off, dinv, csr);

    k_gemm1<<<N_NODES / 16, 256, 0, stream>>>((const float4*)x, (const float4*)W1,
                                              (ushort4*)h1b);
    k_agg1<<<(N_NODES + 3) / 4, 256, 0, stream>>>(off, csr, dinv,
                                                  (const ushortv8*)h1b, (const float4*)b1,
                                                  (float4*)agg1);

    k_gemm2<<<N_NODES / 32, 256, 0, stream>>>((const float4*)agg1, (const float4*)W2,
                                              (float4*)h2);
    k_agg2<<<(N_NODES + 3) / 4, 256, 0, stream>>>(off, csr, dinv,
                                                  (const float4*)h2, (const float4*)b2,
                                                  (float4*)out);
}

// Round 8
// 308.199 us; speedup vs baseline: 1.8458x; 1.5139x over previous
//
#include <hip/hip_runtime.h>

#define N_NODES 100000
#define N_EDGES 1600000
#define IN_DIM 64
#define HID_DIM 128
#define EMB_DIM 64
#define NBUCK 782            // ceil(N_NODES / 128)
#define NBLK  256            // sort chunks
#define CHUNK 6250           // N_EDGES / NBLK
#define NTOT  (NBUCK * NBLK) // 200192 counts

typedef unsigned short ushortv8 __attribute__((ext_vector_type(8)));

__device__ __forceinline__ float bf2f(unsigned short u) {
    return __uint_as_float(((unsigned)u) << 16);
}
__device__ __forceinline__ unsigned short f2bf(float f) {
    unsigned u = __float_as_uint(f);
    unsigned r = (u + 0x7FFFu + ((u >> 16) & 1u)) >> 16;  // RNE
    return (unsigned short)r;
}

// ---------------- edge dtype handling ----------------
__global__ void k_detect_dtype(const unsigned int* __restrict__ ebuf, int* __restrict__ flag) {
    if (blockIdx.x == 0 && threadIdx.x == 0) {
        int is64 = 1;
        for (int i = 0; i < 64; ++i)
            if (ebuf[2 * i + 1] != 0u) { is64 = 0; break; }
        *flag = is64;
    }
}

__device__ __forceinline__ int edge_at(const void* eb, bool is64, long idx) {
    return is64 ? (int)((const long long*)eb)[idx] : ((const int*)eb)[idx];
}

// ------- pass 1: per-(chunk-block, bucket) histogram via LDS ---------------
__global__ __launch_bounds__(1024) void k_hist(const void* __restrict__ eb,
                                               const int* __restrict__ flag,
                                               int* __restrict__ C) {
    __shared__ int h[NBUCK];
    int t = threadIdx.x, b = blockIdx.x;
    for (int i = t; i < NBUCK; i += 1024) h[i] = 0;
    __syncthreads();
    bool is64 = (*flag != 0);
    long e0 = (long)b * CHUNK;
    for (int i = t; i < CHUNK; i += 1024) {
        int c = edge_at(eb, is64, N_EDGES + e0 + i);
        atomicAdd(&h[c >> 7], 1);
    }
    __syncthreads();
    for (int i = t; i < NBUCK; i += 1024) C[i * NBLK + b] = h[i];
}

// ------- hierarchical exclusive scan over NTOT counts ----------------------
__global__ __launch_bounds__(1024) void k_scan1(const int* __restrict__ src,
                                                int* __restrict__ dst,
                                                int* __restrict__ bsum, int n) {
    __shared__ int s[1024];
    int i = blockIdx.x * 1024 + threadIdx.x;
    int v = (i < n) ? src[i] : 0;
    s[threadIdx.x] = v;
    __syncthreads();
    for (int d = 1; d < 1024; d <<= 1) {
        int u = (threadIdx.x >= d) ? s[threadIdx.x - d] : 0;
        __syncthreads();
        s[threadIdx.x] += u;
        __syncthreads();
    }
    if (i < n) dst[i] = s[threadIdx.x] - v;  // exclusive within block
    if (threadIdx.x == 1023) bsum[blockIdx.x] = s[1023];
}

__global__ void k_scan2(int* __restrict__ bsum, int nb) {
    __shared__ int s[256];
    int t = threadIdx.x;
    int v = (t < nb) ? bsum[t] : 0;
    s[t] = v;
    __syncthreads();
    for (int d = 1; d < 256; d <<= 1) {
        int u = (t >= d) ? s[t - d] : 0;
        __syncthreads();
        s[t] += u;
        __syncthreads();
    }
    if (t < nb) bsum[t] = s[t] - v; // exclusive
}

__global__ __launch_bounds__(1024) void k_scan3(int* __restrict__ dst,
                                                const int* __restrict__ bsum, int n) {
    int i = blockIdx.x * 1024 + threadIdx.x;
    if (i < n) dst[i] += bsum[i >> 10];
}

// ------- pass 2: atomic-free scatter (LDS cursors, exact positions) --------
__global__ __launch_bounds__(1024) void k_scatter2(const void* __restrict__ eb,
                                                   const int* __restrict__ flag,
                                                   const int* __restrict__ S,
                                                   unsigned* __restrict__ stage) {
    __shared__ int cur[NBUCK];
    int t = threadIdx.x, b = blockIdx.x;
    for (int i = t; i < NBUCK; i += 1024) cur[i] = S[i * NBLK + b];
    __syncthreads();
    bool is64 = (*flag != 0);
    long e0 = (long)b * CHUNK;
    for (int i = t; i < CHUNK; i += 1024) {
        int r = edge_at(eb, is64, e0 + i);
        int c = edge_at(eb, is64, N_EDGES + e0 + i);
        int p = atomicAdd(&cur[c >> 7], 1);          // LDS atomic
        stage[p] = (unsigned)r | ((unsigned)(c & 127) << 17);  // src<2^17
    }
}

// ------- pass 3: per-bucket finalize: off[], dinv[], csr[] -----------------
__global__ __launch_bounds__(256) void k_bfinal(const unsigned* __restrict__ stage,
                                                const int* __restrict__ S,
                                                int* __restrict__ off,
                                                float* __restrict__ dinv,
                                                int* __restrict__ csr) {
    __shared__ int h[128];
    __shared__ int lcur[128];
    int b = blockIdx.x;
    int t = threadIdx.x;
    int ebase = S[b * NBLK];
    int eend  = (b + 1 < NBUCK) ? S[(b + 1) * NBLK] : N_EDGES;
    if (t < 128) h[t] = 0;
    if (b == 0 && t == 0) off[N_NODES] = N_EDGES;
    __syncthreads();
    for (int i = ebase + t; i < eend; i += 256)
        atomicAdd(&h[stage[i] >> 17], 1);
    __syncthreads();
    int cnt = (t < 128) ? h[t] : 0;
    for (int d = 1; d < 128; d <<= 1) {
        int u = (t < 128 && t >= d) ? h[t - d] : 0;
        __syncthreads();
        if (t < 128) h[t] += u;
        __syncthreads();
    }
    if (t < 128) {
        int node = b * 128 + t;
        int excl = h[t] - cnt;
        lcur[t] = ebase + excl;
        if (node < N_NODES) {
            off[node]  = ebase + excl;
            dinv[node] = rsqrtf((float)(cnt + 1));  // +1 self loop
        }
    }
    __syncthreads();
    for (int i = ebase + t; i < eend; i += 256) {
        unsigned u = stage[i];
        int p = atomicAdd(&lcur[u >> 17], 1);
        csr[p] = (int)(u & 0x1FFFFu);
    }
}

// ---------------- GEMM1: h1b = bf16(x @ W1)  (100000x64 @ 64x128) ----------
__global__ __launch_bounds__(256) void k_gemm1(const float4* __restrict__ x4,
                                               const float4* __restrict__ W14,
                                               ushort4* __restrict__ h1b4) {
    __shared__ float sW[IN_DIM * HID_DIM]; // 32 KB
    __shared__ float sX[16 * IN_DIM];      // 4 KB
    float4* sW4 = (float4*)sW;
    float4* sX4 = (float4*)sX;
    int t = threadIdx.x;
    long row0 = (long)blockIdx.x * 16;
    for (int i = t; i < IN_DIM * HID_DIM / 4; i += 256) sW4[i] = W14[i];
    sX4[t] = x4[row0 * (IN_DIM / 4) + t];  // 256 float4 = 16 rows
    __syncthreads();
    int qc = t & 31;
    int r  = (t >> 5) * 2;
    float4 a0 = {0,0,0,0}, a1 = {0,0,0,0};
    for (int k = 0; k < IN_DIM; ++k) {
        float4 w = sW4[k * 32 + qc];
        float x0 = sX[r * IN_DIM + k];
        float x1 = sX[(r + 1) * IN_DIM + k];
        a0.x += x0 * w.x; a0.y += x0 * w.y; a0.z += x0 * w.z; a0.w += x0 * w.w;
        a1.x += x1 * w.x; a1.y += x1 * w.y; a1.z += x1 * w.z; a1.w += x1 * w.w;
    }
    ushort4 o0, o1;
    o0.x = f2bf(a0.x); o0.y = f2bf(a0.y); o0.z = f2bf(a0.z); o0.w = f2bf(a0.w);
    o1.x = f2bf(a1.x); o1.y = f2bf(a1.y); o1.z = f2bf(a1.z); o1.w = f2bf(a1.w);
    h1b4[(row0 + r) * 32 + qc]     = o0;
    h1b4[(row0 + r + 1) * 32 + qc] = o1;
}

// ------- agg1: 1 wave/node; 4 lane-groups x ushort8 (bf16x8); x4 unroll ----
__global__ __launch_bounds__(256) void k_agg1(const int* __restrict__ off,
                                              const int* __restrict__ csr,
                                              const float* __restrict__ dinv,
                                              const ushortv8* __restrict__ h1b,
                                              const float4* __restrict__ b14,
                                              float4* __restrict__ agg1) {
    int node = blockIdx.x * 4 + (threadIdx.x >> 6);
    if (node >= N_NODES) return;
    int lane = threadIdx.x & 63;
    int grp  = lane >> 4;
    int cpos = lane & 15;
    int ebase = off[node];
    int deg   = off[node + 1] - ebase;
    float dc  = dinv[node];
    float acc[8] = {0.f, 0.f, 0.f, 0.f, 0.f, 0.f, 0.f, 0.f};
    int i = grp;
    for (; i + 12 < deg; i += 16) {
        int s0 = csr[ebase + i + 0];
        int s1 = csr[ebase + i + 4];
        int s2 = csr[ebase + i + 8];
        int s3 = csr[ebase + i + 12];
        float n0 = dc * dinv[s0], n1 = dc * dinv[s1];
        float n2 = dc * dinv[s2], n3 = dc * dinv[s3];
        ushortv8 v0 = h1b[(long)s0 * 16 + cpos];
        ushortv8 v1 = h1b[(long)s1 * 16 + cpos];
        ushortv8 v2 = h1b[(long)s2 * 16 + cpos];
        ushortv8 v3 = h1b[(long)s3 * 16 + cpos];
#pragma unroll
        for (int j = 0; j < 8; ++j) acc[j] += n0 * bf2f(v0[j]);
#pragma unroll
        for (int j = 0; j < 8; ++j) acc[j] += n1 * bf2f(v1[j]);
#pragma unroll
        for (int j = 0; j < 8; ++j) acc[j] += n2 * bf2f(v2[j]);
#pragma unroll
        for (int j = 0; j < 8; ++j) acc[j] += n3 * bf2f(v3[j]);
    }
    for (; i < deg; i += 4) {
        int s = csr[ebase + i];
        float n = dc * dinv[s];
        ushortv8 v = h1b[(long)s * 16 + cpos];
#pragma unroll
        for (int j = 0; j < 8; ++j) acc[j] += n * bf2f(v[j]);
    }
#pragma unroll
    for (int j = 0; j < 8; ++j) {
        acc[j] += __shfl_xor(acc[j], 16);
        acc[j] += __shfl_xor(acc[j], 32);
    }
    if (grp == 0) {
        float s = dc * dc;
        ushortv8 hs = h1b[(long)node * 16 + cpos];
        float4 b0 = b14[2 * cpos], b1 = b14[2 * cpos + 1];
        float4 o0, o1;
        o0.x = b0.x + s * bf2f(hs[0]) + acc[0];
        o0.y = b0.y + s * bf2f(hs[1]) + acc[1];
        o0.z = b0.z + s * bf2f(hs[2]) + acc[2];
        o0.w = b0.w + s * bf2f(hs[3]) + acc[3];
        o1.x = b1.x + s * bf2f(hs[4]) + acc[4];
        o1.y = b1.y + s * bf2f(hs[5]) + acc[5];
        o1.z = b1.z + s * bf2f(hs[6]) + acc[6];
        o1.w = b1.w + s * bf2f(hs[7]) + acc[7];
        agg1[(long)node * 32 + 2 * cpos]     = o0;
        agg1[(long)node * 32 + 2 * cpos + 1] = o1;
    }
}

// ------- GEMM2: h2b = bf16(relu(agg1) @ W2)  (100000x128 @ 128x64) --------
__global__ __launch_bounds__(256) void k_gemm2(const float4* __restrict__ agg14,
                                               const float4* __restrict__ W24,
                                               ushort4* __restrict__ h2b4) {
    __shared__ float sW[HID_DIM * EMB_DIM]; // 32 KB
    __shared__ float sH[32 * HID_DIM];      // 16 KB
    float4* sW4 = (float4*)sW;
    float4* sH4 = (float4*)sH;
    int t = threadIdx.x;
    long row0 = (long)blockIdx.x * 32;
    for (int i = t; i < HID_DIM * EMB_DIM / 4; i += 256) sW4[i] = W24[i];
    for (int i = t; i < 32 * HID_DIM / 4; i += 256) {
        float4 v = agg14[row0 * (HID_DIM / 4) + i];
        v.x = fmaxf(v.x, 0.f); v.y = fmaxf(v.y, 0.f);
        v.z = fmaxf(v.z, 0.f); v.w = fmaxf(v.w, 0.f);
        sH4[i] = v;
    }
    __syncthreads();
    int qc = t & 15;
    int r  = (t >> 4) * 2;
    float4 a0 = {0,0,0,0}, a1 = {0,0,0,0};
    for (int k = 0; k < HID_DIM; ++k) {
        float4 w = sW4[k * 16 + qc];
        float x0 = sH[r * HID_DIM + k];
        float x1 = sH[(r + 1) * HID_DIM + k];
        a0.x += x0 * w.x; a0.y += x0 * w.y; a0.z += x0 * w.z; a0.w += x0 * w.w;
        a1.x += x1 * w.x; a1.y += x1 * w.y; a1.z += x1 * w.z; a1.w += x1 * w.w;
    }
    ushort4 o0, o1;
    o0.x = f2bf(a0.x); o0.y = f2bf(a0.y); o0.z = f2bf(a0.z); o0.w = f2bf(a0.w);
    o1.x = f2bf(a1.x); o1.y = f2bf(a1.y); o1.z = f2bf(a1.z); o1.w = f2bf(a1.w);
    h2b4[(row0 + r) * 16 + qc]     = o0;
    h2b4[(row0 + r + 1) * 16 + qc] = o1;
}

// ------- agg2: 1 wave/node; 8 lane-groups x ushort8 (bf16x8); x4 unroll ----
__global__ __launch_bounds__(256) void k_agg2(const int* __restrict__ off,
                                              const int* __restrict__ csr,
                                              const float* __restrict__ dinv,
                                              const ushortv8* __restrict__ h2b,
                                              const float4* __restrict__ b24,
                                              float4* __restrict__ out) {
    int node = blockIdx.x * 4 + (threadIdx.x >> 6);
    if (node >= N_NODES) return;
    int lane = threadIdx.x & 63;
    int grp  = lane >> 3;   // 0..7
    int cpos = lane & 7;    // ushort8 slot: channels 8*cpos..8*cpos+7
    int ebase = off[node];
    int deg   = off[node + 1] - ebase;
    float dc  = dinv[node];
    float acc[8] = {0.f, 0.f, 0.f, 0.f, 0.f, 0.f, 0.f, 0.f};
    int i = grp;
    for (; i + 24 < deg; i += 32) {   // 4 edges per group in flight, stride 8
        int s0 = csr[ebase + i + 0];
        int s1 = csr[ebase + i + 8];
        int s2 = csr[ebase + i + 16];
        int s3 = csr[ebase + i + 24];
        float n0 = dc * dinv[s0], n1 = dc * dinv[s1];
        float n2 = dc * dinv[s2], n3 = dc * dinv[s3];
        ushortv8 v0 = h2b[(long)s0 * 8 + cpos];
        ushortv8 v1 = h2b[(long)s1 * 8 + cpos];
        ushortv8 v2 = h2b[(long)s2 * 8 + cpos];
        ushortv8 v3 = h2b[(long)s3 * 8 + cpos];
#pragma unroll
        for (int j = 0; j < 8; ++j) acc[j] += n0 * bf2f(v0[j]);
#pragma unroll
        for (int j = 0; j < 8; ++j) acc[j] += n1 * bf2f(v1[j]);
#pragma unroll
        for (int j = 0; j < 8; ++j) acc[j] += n2 * bf2f(v2[j]);
#pragma unroll
        for (int j = 0; j < 8; ++j) acc[j] += n3 * bf2f(v3[j]);
    }
    for (; i < deg; i += 8) {
        int s = csr[ebase + i];
        float n = dc * dinv[s];
        ushortv8 v = h2b[(long)s * 8 + cpos];
#pragma unroll
        for (int j = 0; j < 8; ++j) acc[j] += n * bf2f(v[j]);
    }
#pragma unroll
    for (int j = 0; j < 8; ++j) {
        acc[j] += __shfl_xor(acc[j], 8);
        acc[j] += __shfl_xor(acc[j], 16);
        acc[j] += __shfl_xor(acc[j], 32);
    }
    if (grp == 0) {
        float s = dc * dc;
        ushortv8 hs = h2b[(long)node * 8 + cpos];
        float4 b0 = b24[2 * cpos], b1 = b24[2 * cpos + 1];
        float4 o0, o1;
        o0.x = b0.x + s * bf2f(hs[0]) + acc[0];
        o0.y = b0.y + s * bf2f(hs[1]) + acc[1];
        o0.z = b0.z + s * bf2f(hs[2]) + acc[2];
        o0.w = b0.w + s * bf2f(hs[3]) + acc[3];
        o1.x = b1.x + s * bf2f(hs[4]) + acc[4];
        o1.y = b1.y + s * bf2f(hs[5]) + acc[5];
        o1.z = b1.z + s * bf2f(hs[6]) + acc[6];
        o1.w = b1.w + s * bf2f(hs[7]) + acc[7];
        out[(long)node * 16 + 2 * cpos]     = o0;
        out[(long)node * 16 + 2 * cpos + 1] = o1;
    }
}

extern "C" void kernel_launch(void* const* d_in, const int* in_sizes, int n_in,
                              void* d_out, int out_size, void* d_ws, size_t ws_size,
                              hipStream_t stream) {
    const float* x   = (const float*)d_in[0];
    const void*  eb  = d_in[1];
    const float* W1  = (const float*)d_in[2];
    const float* b1  = (const float*)d_in[3];
    const float* W2  = (const float*)d_in[4];
    const float* b2  = (const float*)d_in[5];
    float* out = (float*)d_out;

    // Workspace layout (bytes):
    char* ws = (char*)d_ws;
    int*            flag  = (int*)     (ws + 0);          //        16
    int*            bsum  = (int*)     (ws + 64);         //       784 (196 ints)
    int*            C     = (int*)     (ws + 1024);       //   800,768
    int*            S     = (int*)     (ws + 802816);     //   800,768
    int*            off   = (int*)     (ws + 1605632);    //   400,004
    float*          dinv  = (float*)   (ws + 2005760);    //   400,000
    unsigned*       stage = (unsigned*)(ws + 2405760);    // 6,400,000
    int*            csr   = (int*)     (ws + 8805760);    // 6,400,000
    unsigned short* h1b   = (unsigned short*)(ws + 15205760); // 25,600,000
    unsigned short* h2b   = (unsigned short*)(ws + 15205760); // alias h1b (dead after agg1)
    float*          agg1  = (float*)   (ws + 40805760);   // 51,200,000 (end ~92.0 MB)

    k_detect_dtype<<<1, 64, 0, stream>>>((const unsigned int*)eb, flag);
    k_hist<<<NBLK, 1024, 0, stream>>>(eb, flag, C);
    const int nsb = (NTOT + 1023) / 1024;   // 196
    k_scan1<<<nsb, 1024, 0, stream>>>(C, S, bsum, NTOT);
    k_scan2<<<1, 256, 0, stream>>>(bsum, nsb);
    k_scan3<<<nsb, 1024, 0, stream>>>(S, bsum, NTOT);
    k_scatter2<<<NBLK, 1024, 0, stream>>>(eb, flag, S, stage);
    k_bfinal<<<NBUCK, 256, 0, stream>>>(stage, S, off, dinv, csr);

    k_gemm1<<<N_NODES / 16, 256, 0, stream>>>((const float4*)x, (const float4*)W1,
                                              (ushort4*)h1b);
    k_agg1<<<(N_NODES + 3) / 4, 256, 0, stream>>>(off, csr, dinv,
                                                  (const ushortv8*)h1b, (const float4*)b1,
                                                  (float4*)agg1);

    k_gemm2<<<N_NODES / 32, 256, 0, stream>>>((const float4*)agg1, (const float4*)W2,
                                              (ushort4*)h2b);
    k_agg2<<<(N_NODES + 3) / 4, 256, 0, stream>>>(off, csr, dinv,
                                                  (const ushortv8*)h2b, (const float4*)b2,
                                                  (float4*)out);
}